// Round 11
// baseline (151.654 us; speedup 1.0000x reference)
//
#include <hip/hip_runtime.h>
#include <cmath>

#define WIN 11
#define HALO 5
#define IMG 512
#define NIMG 48
#define TS 64                         /* output tile: 64x64 */
#define HR (TS + 2*HALO)              /* 74 h-blurred rows held in LDS */
#define NTILE (IMG/TS)                /* 8 tiles per axis */
#define NTT (NIMG*NTILE*NTILE)        /* 3072 tiles total */
#define PBLK 512                      /* persistent blocks */
#define TPB (NTT/PBLK)                /* 6 tiles per block */
#define NPIX (16.0 * 3.0 * 512.0 * 512.0)

typedef _Float16 f16;
typedef _Float16 h2 __attribute__((ext_vector_type(2)));

/* packed fp16 {w,w} weights, built on host -> kernarg -> SGPR operands */
struct GaussW { unsigned hw[WIN]; };

__device__ __forceinline__ unsigned pk2(float a, float b) {
    auto h = __builtin_amdgcn_cvt_pkrtz(a, b);
    return __builtin_bit_cast(unsigned, h);
}
__device__ __forceinline__ h2 uph(unsigned u) {
    return __builtin_bit_cast(h2, u);
}
__device__ __forceinline__ unsigned dnh(h2 v) {
    return __builtin_bit_cast(unsigned, v);
}

__global__ void __launch_bounds__(64) zero_kernel(float* out) {
    if (threadIdx.x == 0) out[0] = 0.f;
}

__global__ void __launch_bounds__(64) finish_kernel(float* out) {
    if (threadIdx.x == 0)
        out[0] = 1.0f - out[0] * (float)(1.0 / NPIX);
}

// ------------- Persistent fused SSIM: 512 blocks x 6 tiles, pipelined -------
// R10 post-mortem: pipeline intact (VGPR=52 = exactly the prefetch live
// set), FETCH 92->63MB, but per-tile cost 5.2us vs ~2us VALU content.
// Phase 2's 12 ds_read_b128/thread = 384 wave-reads x 12cy = 1.9us/tile
// serial at the per-CU LDS unit -> the v-blur was LDS-throughput-bound.
// This version: col-split phase 2.  The uint4 layout already puts one
// COLUMN's two field-pairs {c0,c1} in an aligned 8B half, so 64 col-slots
// x 16 rowgroups x 4 rows: 14 ds_read_b64/thread (lane addr = row*512 +
// lane*8, contiguous, conflict-free) = -60% LDS read time.  Identical tap
// arithmetic per pixel (same chains, same order).
template<int USE_ATOMIC>
__global__ void __launch_bounds__(1024, 4) fused_ssim(
        const float* __restrict__ xin, const float* __restrict__ yin,
        float* __restrict__ outp, GaussW W) {
    __shared__ uint4 hb[HR][32];      /* 74 * 512B = 37,888 B */
    __shared__ float wsum[16];
    const int tid = threadIdx.x;
    /* phase-1 mapping: 8 cols/thread, 74 rows -> threads 0..591 active */
    const int cg = tid & 7;
    const int r  = tid >> 3;          /* 0..127, active if r < HR */
    /* phase-2 mapping: 64 col-slots x 16 rowgroups of 4 output rows */
    const int cidx  = tid & 63;       /* column 0..63 */
    const int rbase = (tid >> 6) * 4; /* first of 14 input rows */

    const int t0 = blockIdx.x * TPB;

    float xv[18], yv[18];             /* prefetch buffer (held across phase2) */
    float local = 0.f;

    /* ---- issue global loads for tile t into xv/yv (registers) ---- */
    auto prefetch = [&](int t) {
        if (r >= HR) return;
        const int tg  = t0 + t;
        const int img = tg >> 6;
        const int rem = tg & 63;
        const int ty  = rem >> 3;
        const int tx  = rem & 7;
        const float* xb = xin + (size_t)img * (IMG * IMG);
        const float* yb = yin + (size_t)img * (IMG * IMG);
        const int gy  = ty * TS - HALO + r;
        const int gx0 = tx * TS + cg * 8 - HALO;   /* 18-col window */
        const bool rowok = ((unsigned)gy < IMG);
        const float* xr = xb + (size_t)gy * IMG;
        const float* yr = yb + (size_t)gy * IMG;
        if (rowok && gx0 >= 0 && gx0 + 17 < IMG) {
            xv[0] = xr[gx0];  yv[0] = yr[gx0];
            #pragma unroll
            for (int q = 0; q < 4; ++q) {          /* 16B-aligned float4s */
                float4 a = *(const float4*)(xr + gx0 + 1 + 4*q);
                float4 b = *(const float4*)(yr + gx0 + 1 + 4*q);
                xv[1+4*q]=a.x; xv[2+4*q]=a.y; xv[3+4*q]=a.z; xv[4+4*q]=a.w;
                yv[1+4*q]=b.x; yv[2+4*q]=b.y; yv[3+4*q]=b.z; yv[4+4*q]=b.w;
            }
            xv[17] = xr[gx0 + 17];  yv[17] = yr[gx0 + 17];
        } else {
            #pragma unroll
            for (int j = 0; j < 18; ++j) {
                int gx = gx0 + j;
                bool ok = rowok && ((unsigned)gx < IMG);
                xv[j] = ok ? xr[gx] : 0.f;
                yv[j] = ok ? yr[gx] : 0.f;
            }
        }
    };

    /* ---- packed fp16 h-blur of the register window -> LDS row ---- */
    auto hblur = [&]() {
        if (r >= HR) return;
        h2 a0[8], a1[8];
        #pragma unroll
        for (int o = 0; o < 8; ++o) {
            a0[o] = (h2){(f16)0, (f16)0};
            a1[o] = (h2){(f16)0, (f16)0};
        }
        #pragma unroll
        for (int j = 0; j < 18; ++j) {
            float xs = xv[j], ys = yv[j];
            h2 c0 = uph(pk2(xs, ys));
            h2 c1 = uph(pk2(fmaf(xs, xs, ys * ys), xs * ys));
            #pragma unroll
            for (int o = 0; o < 8; ++o) {
                int k = j - o;
                if (k >= 0 && k < WIN) {
                    h2 wk = uph(W.hw[k]);          /* SGPR operand */
                    a0[o] += wk * c0;
                    a1[o] += wk * c1;
                }
            }
        }
        /* col-pair p of this thread -> slot cg + 8p (16B lane stride) */
        #pragma unroll
        for (int p = 0; p < 4; ++p) {
            uint4 u;
            u.x = dnh(a0[2*p]);     u.y = dnh(a1[2*p]);
            u.z = dnh(a0[2*p + 1]); u.w = dnh(a1[2*p + 1]);
            hb[r][cg + 8*p] = u;
        }
    };

    /* ---- v-blur + SSIM for current LDS tile, accumulate into local ----
       col-split: one column per thread, 4 output rows, 14 ds_read_b64. */
    auto phase2 = [&]() {
        h2 accm[4], accs[4];
        #pragma unroll
        for (int o = 0; o < 4; ++o) {
            accm[o] = (h2){(f16)0, (f16)0};
            accs[o] = (h2){(f16)0, (f16)0};
        }
        #pragma unroll
        for (int j = 0; j < 14; ++j) {
            const uint2* rowp = (const uint2*)hb[rbase + j];
            uint2 u = rowp[cidx];
            h2 c0 = uph(u.x), c1 = uph(u.y);
            #pragma unroll
            for (int o = 0; o < 4; ++o) {
                int k = j - o;
                if (k >= 0 && k < WIN) {
                    h2 wk = uph(W.hw[k]);
                    accm[o] += wk * c0;
                    accs[o] += wk * c1;
                }
            }
        }
        const float C1 = 0.01f * 0.01f;
        const float C2 = 0.03f * 0.03f;
        #pragma unroll
        for (int o = 0; o < 4; ++o) {
            float mux = (float)accm[o][0];
            float muy = (float)accm[o][1];
            float es  = (float)accs[o][0];         /* E[x^2 + y^2] */
            float exy = (float)accs[o][1];
            float mux2 = mux*mux, muy2 = muy*muy, muxy = mux*muy;
            float num = (2.f*muxy + C1) * (2.f*(exy - muxy) + C2);
            float den = (mux2 + muy2 + C1) * ((es - mux2 - muy2) + C2);
            local += num * __builtin_amdgcn_rcpf(den + 1e-8f);
        }
    };

    /* ---- pipeline: prologue pays load latency once ---- */
    prefetch(0);
    hblur();                          /* consumes tile 0 regs */
    prefetch(1);                      /* tile 1 in flight/regs */
    __syncthreads();

    for (int t = 0; t < TPB; ++t) {
        phase2();                     /* tile t from LDS; t+1 loads hidden */
        if (t + 1 < TPB) {
            __syncthreads();          /* phase2 reads done */
            hblur();                  /* tile t+1 regs -> LDS */
            if (t + 2 < TPB) {
                prefetch(t + 2);      /* issue next loads */
                __builtin_amdgcn_sched_barrier(0);  /* pin issue point */
            }
            __syncthreads();          /* hb ready */
        }
    }

    /* ---- block reduce: one partial per block ---- */
    #pragma unroll
    for (int off = 32; off > 0; off >>= 1)
        local += __shfl_down(local, off, 64);
    if ((tid & 63) == 0) wsum[tid >> 6] = local;
    __syncthreads();
    if (tid == 0) {
        float bs = 0.f;
        #pragma unroll
        for (int wv = 0; wv < 16; ++wv) bs += wsum[wv];
        if (USE_ATOMIC) {
            atomicAdd(outp, bs);
        } else {
            outp[blockIdx.x] = bs;
        }
    }
}

// ---------------- Final reduce: 512 partials -> out[0], one block -----------
__global__ void __launch_bounds__(256) reduce_kernel(
        const float* __restrict__ partial, float* __restrict__ out) {
    __shared__ float wsum[4];
    const int tid = threadIdx.x;
    float s = 0.f;
    for (int i = tid; i < PBLK; i += 256) s += partial[i];
    #pragma unroll
    for (int off = 32; off > 0; off >>= 1)
        s += __shfl_down(s, off, 64);
    if ((tid & 63) == 0) wsum[tid >> 6] = s;
    __syncthreads();
    if (tid == 0)
        out[0] = 1.0f - (wsum[0] + wsum[1] + wsum[2] + wsum[3]) * (float)(1.0 / NPIX);
}

extern "C" void kernel_launch(void* const* d_in, const int* in_sizes, int n_in,
                              void* d_out, int out_size, void* d_ws, size_t ws_size,
                              hipStream_t stream) {
    const float* x = (const float*)d_in[0];
    const float* y = (const float*)d_in[1];
    float* out = (float*)d_out;

    /* fp32 Gaussian weights */
    double g[WIN], s = 0.0;
    for (int i = 0; i < WIN; ++i) {
        double d = (double)(i - WIN / 2);
        g[i] = exp(-(d * d) / (2.0 * 1.5 * 1.5));
        s += g[i];
    }
    float wf[WIN];
    for (int i = 0; i < WIN; ++i) wf[i] = (float)(g[i] / s);

    /* pack to fp16 {w,w}; renormalize center tap so fp16 weight sum == 1 */
    GaussW gw;
    _Float16 wh[WIN];
    double hsum = 0.0;
    for (int i = 0; i < WIN; ++i) { wh[i] = (_Float16)wf[i]; hsum += (double)(float)wh[i]; }
    wh[WIN/2] = (_Float16)((float)wh[WIN/2] + (float)(1.0 - hsum));
    for (int i = 0; i < WIN; ++i) {
        unsigned short b = __builtin_bit_cast(unsigned short, wh[i]);
        gw.hw[i] = (unsigned)b | ((unsigned)b << 16);
    }

    if (ws_size >= (size_t)PBLK * sizeof(float)) {
        float* partial = (float*)d_ws;
        hipLaunchKernelGGL((fused_ssim<0>), dim3(PBLK), dim3(1024),
                           0, stream, x, y, partial, gw);
        hipLaunchKernelGGL(reduce_kernel, dim3(1), dim3(256), 0, stream,
                           partial, out);
    } else {
        hipLaunchKernelGGL(zero_kernel, dim3(1), dim3(64), 0, stream, out);
        hipLaunchKernelGGL((fused_ssim<1>), dim3(PBLK), dim3(1024),
                           0, stream, x, y, out, gw);
        hipLaunchKernelGGL(finish_kernel, dim3(1), dim3(64), 0, stream, out);
    }
}

// Round 12
// 150.567 us; speedup vs baseline: 1.0072x; 1.0072x over previous
//
#include <hip/hip_runtime.h>
#include <cmath>

#define WIN 11
#define HALO 5
#define IMG 512
#define NIMG 48
#define TS 64                         /* output tile: 64x64 */
#define HR (TS + 2*HALO)              /* 74 h-blurred rows held in LDS */
#define NTILE (IMG/TS)                /* 8 tiles per axis */
#define NTT (NIMG*NTILE*NTILE)        /* 3072 tiles total */
#define PBLK 512                      /* persistent blocks */
#define TPB (NTT/PBLK)                /* 6 tiles per block */
#define NPIX (16.0 * 3.0 * 512.0 * 512.0)

typedef _Float16 f16;
typedef _Float16 h2 __attribute__((ext_vector_type(2)));

/* packed fp16 {w,w} weights, built on host -> kernarg -> SGPR operands */
struct GaussW { unsigned hw[WIN]; };

__device__ __forceinline__ unsigned pk2(float a, float b) {
    auto h = __builtin_amdgcn_cvt_pkrtz(a, b);
    return __builtin_bit_cast(unsigned, h);
}
__device__ __forceinline__ h2 uph(unsigned u) {
    return __builtin_bit_cast(h2, u);
}
__device__ __forceinline__ unsigned dnh(h2 v) {
    return __builtin_bit_cast(unsigned, v);
}

/* barrier that orders LDS only: does NOT drain vmcnt, so register-prefetch
   global loads stay in flight across it.  (__syncthreads compiles to
   s_waitcnt vmcnt(0) lgkmcnt(0) + s_barrier, which kills the pipeline.) */
__device__ __forceinline__ void bar_lds() {
    asm volatile("s_waitcnt lgkmcnt(0)" ::: "memory");
    __builtin_amdgcn_s_barrier();
}

__global__ void __launch_bounds__(64) zero_kernel(float* out) {
    if (threadIdx.x == 0) out[0] = 0.f;
}

__global__ void __launch_bounds__(64) finish_kernel(float* out) {
    if (threadIdx.x == 0)
        out[0] = 1.0f - out[0] * (float)(1.0 / NPIX);
}

// ------------- Persistent fused SSIM: 512 blocks x 6 tiles, pipelined -------
// R11 post-mortem: col-split b64 phase2 REGRESSED (62->74us) with identical
// VALU-busy time -> phase2 was not LDS-bound; reverted to R10's b128 form.
// The real stall: __syncthreads drains vmcnt(0), so the t+2 register
// prefetch (issued right before the trailing barrier) was WAITED ON at
// that barrier -- pipeline defeated, every tile paid full load latency.
// This version: lgkmcnt-only barriers (bar_lds) let prefetch loads fly
// across the barrier and complete under the next phase2.
template<int USE_ATOMIC>
__global__ void __launch_bounds__(1024, 4) fused_ssim(
        const float* __restrict__ xin, const float* __restrict__ yin,
        float* __restrict__ outp, GaussW W) {
    __shared__ uint4 hb[HR][32];      /* 74 * 512B = 37,888 B */
    __shared__ float wsum[16];
    const int tid = threadIdx.x;
    /* phase-1 mapping: 8 cols/thread, 74 rows -> threads 0..591 active */
    const int cg = tid & 7;
    const int r  = tid >> 3;          /* 0..127, active if r < HR */
    /* phase-2 mapping: 32 col-pair slots x 32 rowgroups x 2 rows */
    const int idx   = tid & 31;
    const int rbase = (tid >> 5) * 2;

    const int t0 = blockIdx.x * TPB;

    float xv[18], yv[18];             /* prefetch buffer (held across phase2) */
    float local = 0.f;

    /* ---- issue global loads for tile t into xv/yv (registers) ---- */
    auto prefetch = [&](int t) {
        if (r >= HR) return;
        const int tg  = t0 + t;
        const int img = tg >> 6;
        const int rem = tg & 63;
        const int ty  = rem >> 3;
        const int tx  = rem & 7;
        const float* xb = xin + (size_t)img * (IMG * IMG);
        const float* yb = yin + (size_t)img * (IMG * IMG);
        const int gy  = ty * TS - HALO + r;
        const int gx0 = tx * TS + cg * 8 - HALO;   /* 18-col window */
        const bool rowok = ((unsigned)gy < IMG);
        const float* xr = xb + (size_t)gy * IMG;
        const float* yr = yb + (size_t)gy * IMG;
        if (rowok && gx0 >= 0 && gx0 + 17 < IMG) {
            xv[0] = xr[gx0];  yv[0] = yr[gx0];
            #pragma unroll
            for (int q = 0; q < 4; ++q) {          /* 16B-aligned float4s */
                float4 a = *(const float4*)(xr + gx0 + 1 + 4*q);
                float4 b = *(const float4*)(yr + gx0 + 1 + 4*q);
                xv[1+4*q]=a.x; xv[2+4*q]=a.y; xv[3+4*q]=a.z; xv[4+4*q]=a.w;
                yv[1+4*q]=b.x; yv[2+4*q]=b.y; yv[3+4*q]=b.z; yv[4+4*q]=b.w;
            }
            xv[17] = xr[gx0 + 17];  yv[17] = yr[gx0 + 17];
        } else {
            #pragma unroll
            for (int j = 0; j < 18; ++j) {
                int gx = gx0 + j;
                bool ok = rowok && ((unsigned)gx < IMG);
                xv[j] = ok ? xr[gx] : 0.f;
                yv[j] = ok ? yr[gx] : 0.f;
            }
        }
    };

    /* ---- packed fp16 h-blur of the register window -> LDS row ---- */
    auto hblur = [&]() {
        if (r >= HR) return;
        h2 a0[8], a1[8];
        #pragma unroll
        for (int o = 0; o < 8; ++o) {
            a0[o] = (h2){(f16)0, (f16)0};
            a1[o] = (h2){(f16)0, (f16)0};
        }
        #pragma unroll
        for (int j = 0; j < 18; ++j) {
            float xs = xv[j], ys = yv[j];
            h2 c0 = uph(pk2(xs, ys));
            h2 c1 = uph(pk2(fmaf(xs, xs, ys * ys), xs * ys));
            #pragma unroll
            for (int o = 0; o < 8; ++o) {
                int k = j - o;
                if (k >= 0 && k < WIN) {
                    h2 wk = uph(W.hw[k]);          /* SGPR operand */
                    a0[o] += wk * c0;
                    a1[o] += wk * c1;
                }
            }
        }
        /* col-pair p of this thread -> slot cg + 8p (16B lane stride) */
        #pragma unroll
        for (int p = 0; p < 4; ++p) {
            uint4 u;
            u.x = dnh(a0[2*p]);     u.y = dnh(a1[2*p]);
            u.z = dnh(a0[2*p + 1]); u.w = dnh(a1[2*p + 1]);
            hb[r][cg + 8*p] = u;
        }
    };

    /* ---- v-blur + SSIM for current LDS tile, accumulate into local ---- */
    auto phase2 = [&]() {
        h2 acc[2][4];
        #pragma unroll
        for (int o = 0; o < 2; ++o)
            #pragma unroll
            for (int f = 0; f < 4; ++f)
                acc[o][f] = (h2){(f16)0, (f16)0};
        #pragma unroll
        for (int j = 0; j < 12; ++j) {
            uint4 u = hb[rbase + j][idx];
            h2 f0 = uph(u.x), f1 = uph(u.y), f2 = uph(u.z), f3 = uph(u.w);
            #pragma unroll
            for (int o = 0; o < 2; ++o) {
                int k = j - o;
                if (k >= 0 && k < WIN) {
                    h2 wk = uph(W.hw[k]);
                    acc[o][0] += wk * f0;
                    acc[o][1] += wk * f1;
                    acc[o][2] += wk * f2;
                    acc[o][3] += wk * f3;
                }
            }
        }
        const float C1 = 0.01f * 0.01f;
        const float C2 = 0.03f * 0.03f;
        #pragma unroll
        for (int o = 0; o < 2; ++o) {
            #pragma unroll
            for (int p = 0; p < 2; ++p) {
                h2 m  = acc[o][2*p];               /* {mu_x, mu_y}   */
                h2 se = acc[o][2*p + 1];           /* {E[ss], E[xy]} */
                float mux = (float)m[0];
                float muy = (float)m[1];
                float es  = (float)se[0];
                float exy = (float)se[1];
                float mux2 = mux*mux, muy2 = muy*muy, muxy = mux*muy;
                float num = (2.f*muxy + C1) * (2.f*(exy - muxy) + C2);
                float den = (mux2 + muy2 + C1) * ((es - mux2 - muy2) + C2);
                local += num * __builtin_amdgcn_rcpf(den + 1e-8f);
            }
        }
    };

    /* ---- pipeline: prologue pays load latency once ---- */
    prefetch(0);
    hblur();                          /* consumes tile 0 regs */
    prefetch(1);                      /* tile 1 in flight/regs */
    bar_lds();

    for (int t = 0; t < TPB; ++t) {
        phase2();                     /* tile t from LDS; t+1 loads hidden */
        if (t + 1 < TPB) {
            bar_lds();                /* phase2 reads done (lgkm only) */
            hblur();                  /* tile t+1 regs -> LDS */
            if (t + 2 < TPB) {
                prefetch(t + 2);      /* issue next loads; NOT drained below */
                __builtin_amdgcn_sched_barrier(0);  /* pin issue point */
            }
            bar_lds();                /* hb ready; vmcnt stays in flight */
        }
    }

    /* ---- block reduce: one partial per block ---- */
    #pragma unroll
    for (int off = 32; off > 0; off >>= 1)
        local += __shfl_down(local, off, 64);
    if ((tid & 63) == 0) wsum[tid >> 6] = local;
    __syncthreads();
    if (tid == 0) {
        float bs = 0.f;
        #pragma unroll
        for (int wv = 0; wv < 16; ++wv) bs += wsum[wv];
        if (USE_ATOMIC) {
            atomicAdd(outp, bs);
        } else {
            outp[blockIdx.x] = bs;
        }
    }
}

// ---------------- Final reduce: 512 partials -> out[0], one block -----------
__global__ void __launch_bounds__(256) reduce_kernel(
        const float* __restrict__ partial, float* __restrict__ out) {
    __shared__ float wsum[4];
    const int tid = threadIdx.x;
    float s = 0.f;
    for (int i = tid; i < PBLK; i += 256) s += partial[i];
    #pragma unroll
    for (int off = 32; off > 0; off >>= 1)
        s += __shfl_down(s, off, 64);
    if ((tid & 63) == 0) wsum[tid >> 6] = s;
    __syncthreads();
    if (tid == 0)
        out[0] = 1.0f - (wsum[0] + wsum[1] + wsum[2] + wsum[3]) * (float)(1.0 / NPIX);
}

extern "C" void kernel_launch(void* const* d_in, const int* in_sizes, int n_in,
                              void* d_out, int out_size, void* d_ws, size_t ws_size,
                              hipStream_t stream) {
    const float* x = (const float*)d_in[0];
    const float* y = (const float*)d_in[1];
    float* out = (float*)d_out;

    /* fp32 Gaussian weights */
    double g[WIN], s = 0.0;
    for (int i = 0; i < WIN; ++i) {
        double d = (double)(i - WIN / 2);
        g[i] = exp(-(d * d) / (2.0 * 1.5 * 1.5));
        s += g[i];
    }
    float wf[WIN];
    for (int i = 0; i < WIN; ++i) wf[i] = (float)(g[i] / s);

    /* pack to fp16 {w,w}; renormalize center tap so fp16 weight sum == 1 */
    GaussW gw;
    _Float16 wh[WIN];
    double hsum = 0.0;
    for (int i = 0; i < WIN; ++i) { wh[i] = (_Float16)wf[i]; hsum += (double)(float)wh[i]; }
    wh[WIN/2] = (_Float16)((float)wh[WIN/2] + (float)(1.0 - hsum));
    for (int i = 0; i < WIN; ++i) {
        unsigned short b = __builtin_bit_cast(unsigned short, wh[i]);
        gw.hw[i] = (unsigned)b | ((unsigned)b << 16);
    }

    if (ws_size >= (size_t)PBLK * sizeof(float)) {
        float* partial = (float*)d_ws;
        hipLaunchKernelGGL((fused_ssim<0>), dim3(PBLK), dim3(1024),
                           0, stream, x, y, partial, gw);
        hipLaunchKernelGGL(reduce_kernel, dim3(1), dim3(256), 0, stream,
                           partial, out);
    } else {
        hipLaunchKernelGGL(zero_kernel, dim3(1), dim3(64), 0, stream, out);
        hipLaunchKernelGGL((fused_ssim<1>), dim3(PBLK), dim3(1024),
                           0, stream, x, y, out, gw);
        hipLaunchKernelGGL(finish_kernel, dim3(1), dim3(64), 0, stream, out);
    }
}

// Round 15
// 146.647 us; speedup vs baseline: 1.0341x; 1.0267x over previous
//
#include <hip/hip_runtime.h>
#include <cmath>

#define WIN 11
#define HALO 5
#define IMG 512
#define NIMG 48
#define TS 64                         /* output tile: 64x64 */
#define HR (TS + 2*HALO)              /* 74 h-blurred rows held in LDS */
#define NTILE (IMG/TS)                /* 8 tiles per axis */
#define NTT (NIMG*NTILE*NTILE)        /* 3072 tiles total */
#define PBLK 512                      /* persistent blocks */
#define TPB (NTT/PBLK)                /* 6 tiles per block */
#define NPIX (16.0 * 3.0 * 512.0 * 512.0)

typedef _Float16 f16;
typedef _Float16 h2 __attribute__((ext_vector_type(2)));

/* packed fp16 {w,w} weights, built on host -> kernarg -> SGPR operands */
struct GaussW { unsigned hw[WIN]; };

__device__ __forceinline__ unsigned pk2(float a, float b) {
    auto h = __builtin_amdgcn_cvt_pkrtz(a, b);
    return __builtin_bit_cast(unsigned, h);
}
__device__ __forceinline__ h2 uph(unsigned u) {
    return __builtin_bit_cast(h2, u);
}
__device__ __forceinline__ unsigned dnh(h2 v) {
    return __builtin_bit_cast(unsigned, v);
}

/* barrier that orders LDS only: does NOT drain vmcnt, so register-prefetch
   global loads stay in flight across it. */
__device__ __forceinline__ void bar_lds() {
    asm volatile("s_waitcnt lgkmcnt(0)" ::: "memory");
    __builtin_amdgcn_s_barrier();
}

__global__ void __launch_bounds__(64) zero_kernel(float* out) {
    if (threadIdx.x == 0) out[0] = 0.f;
}

__global__ void __launch_bounds__(64) finish_kernel(float* out) {
    if (threadIdx.x == 0)
        out[0] = 1.0f - out[0] * (float)(1.0 / NPIX);
}

// ------------- Persistent fused SSIM: 512 blocks x 6 tiles, dbuf LDS -------
// R12 post-mortem: lgkm-only barriers were a null (64us unchanged) -> the
// stall is the 2-barrier-per-tile phase ALTERNATION: during hblur the LDS
// pipe idles (and 6.75/16 waves park at the barrier); during phase2 the
// VALU half-idles; ~5.3us/tile vs ~1.4us content.
// This version: double-buffered LDS tile + ONE barrier per tile.
//   iter t: hblur(t+1)->buf[(t+1)&1]; prefetch(t+2); phase2(t)<-buf[t&1]; bar
// Write/read parities differ -> no intra-iteration hazard; buf[p] write at
// iter t vs its last read at iter t-1 are barrier-separated.  Waves drift:
// hblur-idle waves run phase2 LDS reads while busy waves do hblur VALU ->
// both pipes fed; critical path ~ max(LDS,VALU) not the sum.  Prefetch is
// issued right after hblur frees xv/yv, covered by phase2.
template<int USE_ATOMIC>
__global__ void __launch_bounds__(1024, 4) fused_ssim(
        const float* __restrict__ xin, const float* __restrict__ yin,
        float* __restrict__ outp, GaussW W) {
    __shared__ uint4 hb[2][HR][32];   /* 2 * 74 * 512B = 75,776 B */
    __shared__ float wsum[16];
    const int tid = threadIdx.x;
    /* phase-1 mapping: 8 cols/thread, 74 rows -> threads 0..591 active */
    const int cg = tid & 7;
    const int r  = tid >> 3;          /* 0..127, active if r < HR */
    /* phase-2 mapping: 32 col-pair slots x 32 rowgroups x 2 rows */
    const int idx   = tid & 31;
    const int rbase = (tid >> 5) * 2;

    const int t0 = blockIdx.x * TPB;

    float xv[18], yv[18];             /* prefetch buffer */
    float local = 0.f;

    /* ---- issue global loads for tile t into xv/yv (registers) ---- */
    auto prefetch = [&](int t) {
        if (r >= HR) return;
        const int tg  = t0 + t;
        const int img = tg >> 6;
        const int rem = tg & 63;
        const int ty  = rem >> 3;
        const int tx  = rem & 7;
        const float* xb = xin + (size_t)img * (IMG * IMG);
        const float* yb = yin + (size_t)img * (IMG * IMG);
        const int gy  = ty * TS - HALO + r;
        const int gx0 = tx * TS + cg * 8 - HALO;   /* 18-col window */
        const bool rowok = ((unsigned)gy < IMG);
        const float* xr = xb + (size_t)gy * IMG;
        const float* yr = yb + (size_t)gy * IMG;
        if (rowok && gx0 >= 0 && gx0 + 17 < IMG) {
            xv[0] = xr[gx0];  yv[0] = yr[gx0];
            #pragma unroll
            for (int q = 0; q < 4; ++q) {          /* 16B-aligned float4s */
                float4 a = *(const float4*)(xr + gx0 + 1 + 4*q);
                float4 b = *(const float4*)(yr + gx0 + 1 + 4*q);
                xv[1+4*q]=a.x; xv[2+4*q]=a.y; xv[3+4*q]=a.z; xv[4+4*q]=a.w;
                yv[1+4*q]=b.x; yv[2+4*q]=b.y; yv[3+4*q]=b.z; yv[4+4*q]=b.w;
            }
            xv[17] = xr[gx0 + 17];  yv[17] = yr[gx0 + 17];
        } else {
            #pragma unroll
            for (int j = 0; j < 18; ++j) {
                int gx = gx0 + j;
                bool ok = rowok && ((unsigned)gx < IMG);
                xv[j] = ok ? xr[gx] : 0.f;
                yv[j] = ok ? yr[gx] : 0.f;
            }
        }
    };

    /* ---- packed fp16 h-blur of the register window -> LDS buf b ---- */
    auto hblur = [&](int b) {
        if (r >= HR) return;
        h2 a0[8], a1[8];
        #pragma unroll
        for (int o = 0; o < 8; ++o) {
            a0[o] = (h2){(f16)0, (f16)0};
            a1[o] = (h2){(f16)0, (f16)0};
        }
        #pragma unroll
        for (int j = 0; j < 18; ++j) {
            float xs = xv[j], ys = yv[j];
            h2 c0 = uph(pk2(xs, ys));
            h2 c1 = uph(pk2(fmaf(xs, xs, ys * ys), xs * ys));
            #pragma unroll
            for (int o = 0; o < 8; ++o) {
                int k = j - o;
                if (k >= 0 && k < WIN) {
                    h2 wk = uph(W.hw[k]);          /* SGPR operand */
                    a0[o] += wk * c0;
                    a1[o] += wk * c1;
                }
            }
        }
        /* col-pair p of this thread -> slot cg + 8p (16B lane stride) */
        #pragma unroll
        for (int p = 0; p < 4; ++p) {
            uint4 u;
            u.x = dnh(a0[2*p]);     u.y = dnh(a1[2*p]);
            u.z = dnh(a0[2*p + 1]); u.w = dnh(a1[2*p + 1]);
            hb[b][r][cg + 8*p] = u;
        }
    };

    /* ---- v-blur + SSIM from LDS buf b, accumulate into local ---- */
    auto phase2 = [&](int b) {
        h2 acc[2][4];
        #pragma unroll
        for (int o = 0; o < 2; ++o)
            #pragma unroll
            for (int f = 0; f < 4; ++f)
                acc[o][f] = (h2){(f16)0, (f16)0};
        #pragma unroll
        for (int j = 0; j < 12; ++j) {
            uint4 u = hb[b][rbase + j][idx];
            h2 f0 = uph(u.x), f1 = uph(u.y), f2 = uph(u.z), f3 = uph(u.w);
            #pragma unroll
            for (int o = 0; o < 2; ++o) {
                int k = j - o;
                if (k >= 0 && k < WIN) {
                    h2 wk = uph(W.hw[k]);
                    acc[o][0] += wk * f0;
                    acc[o][1] += wk * f1;
                    acc[o][2] += wk * f2;
                    acc[o][3] += wk * f3;
                }
            }
        }
        const float C1 = 0.01f * 0.01f;
        const float C2 = 0.03f * 0.03f;
        #pragma unroll
        for (int o = 0; o < 2; ++o) {
            #pragma unroll
            for (int p = 0; p < 2; ++p) {
                h2 m  = acc[o][2*p];               /* {mu_x, mu_y}   */
                h2 se = acc[o][2*p + 1];           /* {E[ss], E[xy]} */
                float mux = (float)m[0];
                float muy = (float)m[1];
                float es  = (float)se[0];
                float exy = (float)se[1];
                float mux2 = mux*mux, muy2 = muy*muy, muxy = mux*muy;
                float num = (2.f*muxy + C1) * (2.f*(exy - muxy) + C2);
                float den = (mux2 + muy2 + C1) * ((es - mux2 - muy2) + C2);
                local += num * __builtin_amdgcn_rcpf(den + 1e-8f);
            }
        }
    };

    /* ---- prologue: tile 0 into buf 0; tile 1 loads in flight ---- */
    prefetch(0);
    hblur(0);
    prefetch(1);
    bar_lds();

    /* ---- main loop: ONE barrier per tile ---- */
    for (int t = 0; t < TPB; ++t) {
        if (t + 1 < TPB) {
            hblur((t + 1) & 1);       /* consumes regs (tile t+1) */
            if (t + 2 < TPB) {
                prefetch(t + 2);      /* refill regs; in flight over phase2 */
                __builtin_amdgcn_sched_barrier(0);
            }
        }
        phase2(t & 1);                /* reads other parity: no hazard */
        bar_lds();
    }

    /* ---- block reduce: one partial per block ---- */
    #pragma unroll
    for (int off = 32; off > 0; off >>= 1)
        local += __shfl_down(local, off, 64);
    if ((tid & 63) == 0) wsum[tid >> 6] = local;
    __syncthreads();
    if (tid == 0) {
        float bs = 0.f;
        #pragma unroll
        for (int wv = 0; wv < 16; ++wv) bs += wsum[wv];
        if (USE_ATOMIC) {
            atomicAdd(outp, bs);
        } else {
            outp[blockIdx.x] = bs;
        }
    }
}

// ---------------- Final reduce: 512 partials -> out[0], one block -----------
__global__ void __launch_bounds__(256) reduce_kernel(
        const float* __restrict__ partial, float* __restrict__ out) {
    __shared__ float wsum[4];
    const int tid = threadIdx.x;
    float s = 0.f;
    for (int i = tid; i < PBLK; i += 256) s += partial[i];
    #pragma unroll
    for (int off = 32; off > 0; off >>= 1)
        s += __shfl_down(s, off, 64);
    if ((tid & 63) == 0) wsum[tid >> 6] = s;
    __syncthreads();
    if (tid == 0)
        out[0] = 1.0f - (wsum[0] + wsum[1] + wsum[2] + wsum[3]) * (float)(1.0 / NPIX);
}

extern "C" void kernel_launch(void* const* d_in, const int* in_sizes, int n_in,
                              void* d_out, int out_size, void* d_ws, size_t ws_size,
                              hipStream_t stream) {
    const float* x = (const float*)d_in[0];
    const float* y = (const float*)d_in[1];
    float* out = (float*)d_out;

    /* fp32 Gaussian weights */
    double g[WIN], s = 0.0;
    for (int i = 0; i < WIN; ++i) {
        double d = (double)(i - WIN / 2);
        g[i] = exp(-(d * d) / (2.0 * 1.5 * 1.5));
        s += g[i];
    }
    float wf[WIN];
    for (int i = 0; i < WIN; ++i) wf[i] = (float)(g[i] / s);

    /* pack to fp16 {w,w}; renormalize center tap so fp16 weight sum == 1 */
    GaussW gw;
    _Float16 wh[WIN];
    double hsum = 0.0;
    for (int i = 0; i < WIN; ++i) { wh[i] = (_Float16)wf[i]; hsum += (double)(float)wh[i]; }
    wh[WIN/2] = (_Float16)((float)wh[WIN/2] + (float)(1.0 - hsum));
    for (int i = 0; i < WIN; ++i) {
        unsigned short b = __builtin_bit_cast(unsigned short, wh[i]);
        gw.hw[i] = (unsigned)b | ((unsigned)b << 16);
    }

    if (ws_size >= (size_t)PBLK * sizeof(float)) {
        float* partial = (float*)d_ws;
        hipLaunchKernelGGL((fused_ssim<0>), dim3(PBLK), dim3(1024),
                           0, stream, x, y, partial, gw);
        hipLaunchKernelGGL(reduce_kernel, dim3(1), dim3(256), 0, stream,
                           partial, out);
    } else {
        hipLaunchKernelGGL(zero_kernel, dim3(1), dim3(64), 0, stream, out);
        hipLaunchKernelGGL((fused_ssim<1>), dim3(PBLK), dim3(1024),
                           0, stream, x, y, out, gw);
        hipLaunchKernelGGL(finish_kernel, dim3(1), dim3(64), 0, stream, out);
    }
}